// Round 8
// baseline (571.214 us; speedup 1.0000x reference)
//
#include <hip/hip_runtime.h>
#include <math.h>

// N=8192 all-pairs wind-influence graph. Output: [edge_attr f32 N*N][mask01 f32 N*N]
//
// Round 8: sparse writes. The output is >99.5% zeros (mask needs infl>0.3 =>
// dist<161km => P~0.05-0.5% for uniform points over ~2775x5300 km). R3-R7
// showed compute+bulk-store kernels plateau at 2.9 TB/s while the runtime fill
// engine sustains 6.3 TB/s on the same buffer. So: zero d_out via
// hipMemsetAsync (stream-ordered, graph-capturable; the harness itself uses
// it), then a scan kernel computes the cheap 7-FMA 'a' per pair and ONLY for
// a <= ACUT (provably-complete superset of mask-true, established round 3)
// runs the full bit-identical pair_body and scatter-stores the survivors.
// Values written are identical to rounds 4-7 -> absmax unchanged.
//
//   tab_i (N,12): s,c,hs,hc,hsl,hcl,sl,cl,swr,cwr,ws10,pad  (i-side)
//   tab_j (N,8):  s,c,hs,hc,hsl,hcl,sl,cl                   (j-side, dense 32B)

#define NN 8192
#define TI_FB 16
#define TJ_FB 1024
#define TABI_FLOATS (NN * 12)
#define TABJ_FLOATS (NN * 8)
#define ACUT 1.9e-4f   // a > ACUT => dist > 175.6 km => infl <= 1.5*e^-1.756 = 0.259 < 0.3

typedef float f4v __attribute__((ext_vector_type(4)));

__global__ __launch_bounds__(256) void precomp_kernel(
    const float* __restrict__ pos,
    const float* __restrict__ wspd,
    const float* __restrict__ wdir,
    float* __restrict__ tab_i,         // (N,12)
    float* __restrict__ tab_j)         // (N,8)
{
    const int i = blockIdx.x * 256 + threadIdx.x;
    if (i >= NN) return;
    const float DEG2RAD = 0.017453292519943295f;
    float latr = pos[2 * i]     * DEG2RAD;
    float lonr = pos[2 * i + 1] * DEG2RAD;
    float wr   = wdir[i]        * DEG2RAD;
    float s, c, hs, hc, hsl, hcl, sl, cl, swr, cwr;
    sincosf(latr,        &s,   &c);
    sincosf(0.5f * latr, &hs,  &hc);
    sincosf(0.5f * lonr, &hsl, &hcl);
    sincosf(lonr,        &sl,  &cl);
    sincosf(wr,          &swr, &cwr);
    float* p = tab_i + i * 12;
    p[0] = s;   p[1] = c;   p[2]  = hs;  p[3]  = hc;
    p[4] = hsl; p[5] = hcl; p[6]  = sl;  p[7]  = cl;
    p[8] = swr; p[9] = cwr; p[10] = wspd[i] / 10.0f; p[11] = 0.0f;
    float* q = tab_j + i * 8;
    q[0] = s;   q[1] = c;   q[2] = hs;  q[3] = hc;
    q[4] = hsl; q[5] = hcl; q[6] = sl;  q[7] = cl;
}

// Full pair math — BIT-IDENTICAL to rounds 4-7.
__device__ __forceinline__ void pair_body(
    float is, float ic, float ihs, float ihc,
    float ihsl, float ihcl, float isl, float icl,
    float swr, float cwr, float ws10,
    float js, float jc, float jhs, float jhc,
    float jhsl, float jhcl, float jsl, float jcl,
    bool offdiag, float* ev, bool* mout)
{
    float shlat = jhs * ihc - jhc * ihs;
    float shlon = jhsl * ihcl - jhcl * ihsl;
    float cc = ic * jc;
    float a = shlat * shlat + cc * (shlon * shlon);
    float ac = fminf(fmaxf(a, 1e-12f), 1.0f);

    float s = sqrtf(ac);
    float s2 = s * s;
    float dist = fmaf(s * s2, 2123.6667f, s * 12742.0f);  // 12742*(s + s^3/6)

    float sdlon = jsl * icl - jcl * isl;
    float cdlon = jcl * icl + jsl * isl;
    float x = sdlon * jc;
    float y = ic * js - (is * jc) * cdlon;

    float num = y * cwr + x * swr;
    float h2  = x * x + y * y;
    float align = num * rsqrtf(h2);           // NaN on diagonal -> compares false

    float infl = align * ws10 * __expf(dist * -0.01f);
    bool m = offdiag && (dist <= 300.0f) && (infl > 0.3f);
    *ev = infl;
    *mout = m;
}

__global__ __launch_bounds__(256) void scan_kernel(
    const float* __restrict__ tab_i,   // (N,12)
    const float* __restrict__ tab_j,   // (N,8)
    float* __restrict__ out)           // 2*N*N floats (pre-zeroed)
{
    const int tid   = threadIdx.x;
    const int i0    = blockIdx.y * 16;
    const int jbase = blockIdx.x * 1024 + tid * 4;

    // j-side values: loaded once, reused across 16 i-rows
    float js[4], jc[4], jhs[4], jhc[4], jhsl[4], jhcl[4], jsl[4], jcl[4];
    #pragma unroll
    for (int k = 0; k < 4; ++k) {
        const float4* q = (const float4*)tab_j + (size_t)(jbase + k) * 2;
        float4 A = q[0], B = q[1];
        js[k]   = A.x; jc[k]   = A.y; jhs[k] = A.z; jhc[k] = A.w;
        jhsl[k] = B.x; jhcl[k] = B.y; jsl[k] = B.z; jcl[k] = B.w;
    }

    #pragma unroll 1
    for (int r = 0; r < 16; ++r) {
        const int i = i0 + r;
        const float4* p4 = (const float4*)(tab_i + (size_t)i * 12); // block-uniform
        float4 A = p4[0], B = p4[1], C = p4[2];

        #pragma unroll
        for (int k = 0; k < 4; ++k) {
            // cheap screen: same ops as pair_body's 'a'
            float shlat = jhs[k] * A.w - jhc[k] * A.z;
            float shlon = jhsl[k] * B.y - jhcl[k] * B.x;
            float cc = A.y * jc[k];
            float a = shlat * shlat + cc * (shlon * shlon);

            if (a <= ACUT) {   // ~0.6% of pairs + diagonal
                float e; bool m;
                pair_body(A.x, A.y, A.z, A.w, B.x, B.y, B.z, B.w, C.x, C.y, C.z,
                          js[k], jc[k], jhs[k], jhc[k], jhsl[k], jhcl[k], jsl[k], jcl[k],
                          (jbase + k) != i, &e, &m);
                if (m) {
                    size_t idx = (size_t)i * NN + jbase + k;
                    out[idx] = e;
                    out[(size_t)NN * NN + idx] = 1.0f;
                }
            }
        }
    }
}

// ---- fallback if ws too small: round-5 structure (full dense write) ----
__global__ __launch_bounds__(256) void dyn_graph_kernel_fb(
    const float* __restrict__ pos,
    const float* __restrict__ wspd,
    const float* __restrict__ wdir,
    float* __restrict__ out)
{
    __shared__ __align__(16) float irow[TI_FB * 12];
    const int tid   = threadIdx.x;
    const int i0    = blockIdx.y * TI_FB;
    const int jbase = blockIdx.x * TJ_FB + tid * 4;
    const float DEG2RAD = 0.017453292519943295f;

    if (tid < TI_FB) {
        int i = i0 + tid;
        float latr = pos[2 * i]     * DEG2RAD;
        float lonr = pos[2 * i + 1] * DEG2RAD;
        float wr   = wdir[i]        * DEG2RAD;
        float s, c, hs, hc, hsl, hcl, sl, cl, swr, cwr;
        sincosf(latr,        &s,   &c);
        sincosf(0.5f * latr, &hs,  &hc);
        sincosf(0.5f * lonr, &hsl, &hcl);
        sincosf(lonr,        &sl,  &cl);
        sincosf(wr,          &swr, &cwr);
        float* p = &irow[tid * 12];
        p[0] = s;   p[1] = c;   p[2]  = hs;  p[3]  = hc;
        p[4] = hsl; p[5] = hcl; p[6]  = sl;  p[7]  = cl;
        p[8] = swr; p[9] = cwr; p[10] = wspd[i] / 10.0f; p[11] = 0.0f;
    }

    float4 p01 = *(const float4*)(pos + 2 * jbase);
    float4 p23 = *(const float4*)(pos + 2 * jbase + 4);
    float jlat[4] = { p01.x, p01.z, p23.x, p23.z };
    float jlon[4] = { p01.y, p01.w, p23.y, p23.w };
    float js[4], jcv[4], jhs[4], jhc[4], jhsl[4], jhcl[4], jsl[4], jcl[4];
    #pragma unroll
    for (int k = 0; k < 4; ++k) {
        float latr = jlat[k] * DEG2RAD;
        float lonr = jlon[k] * DEG2RAD;
        sincosf(latr,        &js[k],   &jcv[k]);
        sincosf(0.5f * latr, &jhs[k],  &jhc[k]);
        sincosf(0.5f * lonr, &jhsl[k], &jhcl[k]);
        sincosf(lonr,        &jsl[k],  &jcl[k]);
    }
    __syncthreads();

    #pragma unroll 1
    for (int r = 0; r < TI_FB; ++r) {
        const float4* p4 = (const float4*)&irow[r * 12];
        float4 A = p4[0], B = p4[1], C = p4[2];
        const int i = i0 + r;
        f4v ev, mv;
        #pragma unroll
        for (int k = 0; k < 4; ++k) {
            float e; bool m;
            pair_body(A.x, A.y, A.z, A.w, B.x, B.y, B.z, B.w, C.x, C.y, C.z,
                      js[k], jcv[k], jhs[k], jhc[k], jhsl[k], jhcl[k], jsl[k], jcl[k],
                      (jbase + k) != i, &e, &m);
            ev[k] = m ? e : 0.0f; mv[k] = m ? 1.0f : 0.0f;
        }
        size_t idx = (size_t)i * NN + jbase;
        __builtin_nontemporal_store(ev, (f4v*)(out + idx));
        __builtin_nontemporal_store(mv, (f4v*)(out + (size_t)NN * NN + idx));
    }
}

extern "C" void kernel_launch(void* const* d_in, const int* in_sizes, int n_in,
                              void* d_out, int out_size, void* d_ws, size_t ws_size,
                              hipStream_t stream) {
    const float* pos  = (const float*)d_in[0];
    const float* wspd = (const float*)d_in[1];
    const float* wdir = (const float*)d_in[2];
    float* out = (float*)d_out;

    if (ws_size >= (size_t)(TABI_FLOATS + TABJ_FLOATS) * sizeof(float)) {
        // zero the output via the fill engine (6.3 TB/s), then sparse-write survivors
        hipMemsetAsync(d_out, 0, (size_t)out_size * sizeof(float), stream);
        float* tab_i = (float*)d_ws;
        float* tab_j = tab_i + TABI_FLOATS;
        precomp_kernel<<<dim3(NN / 256), dim3(256), 0, stream>>>(pos, wspd, wdir, tab_i, tab_j);
        scan_kernel<<<dim3(8, 512), dim3(256), 0, stream>>>(tab_i, tab_j, out);
    } else {
        dim3 grid(NN / TJ_FB, NN / TI_FB);
        dyn_graph_kernel_fb<<<grid, dim3(256), 0, stream>>>(pos, wspd, wdir, out);
    }
}